// Round 1
// baseline (935.685 us; speedup 1.0000x reference)
//
#include <hip/hip_runtime.h>
#include <hip/hip_bf16.h>

#define N_NODES  100000
#define N_EDGES  1600000
#define N_GRAPHS 2000
#define N_FEAT   13
#define HID      128

// -------------------- degree / dinv --------------------
__global__ void k_deg(const int* __restrict__ dst, int* __restrict__ indeg, int E) {
    int e = blockIdx.x * 256 + threadIdx.x;
    if (e < E) atomicAdd(&indeg[dst[e]], 1);
}

__global__ void k_dinv(const int* __restrict__ indeg, float* __restrict__ dinv, int n) {
    int i = blockIdx.x * 256 + threadIdx.x;
    if (i < n) dinv[i] = rsqrtf((float)(indeg[i] + 1));   // +1 self loop; deg >= 1 always
}

// -------------------- scans (exclusive) --------------------
// level-1: blocks of 1024 elements (256 thr x 4 each); writes local-exclusive + block sums
__global__ void k_scan1(const int* __restrict__ in, int* __restrict__ out,
                        int* __restrict__ bsum, int n) {
    __shared__ int ts[256];
    int t = threadIdx.x;
    int base = blockIdx.x * 1024 + t * 4;
    int v0 = (base + 0 < n) ? in[base + 0] : 0;
    int v1 = (base + 1 < n) ? in[base + 1] : 0;
    int v2 = (base + 2 < n) ? in[base + 2] : 0;
    int v3 = (base + 3 < n) ? in[base + 3] : 0;
    int s = v0 + v1 + v2 + v3;
    ts[t] = s;
    __syncthreads();
    for (int o = 1; o < 256; o <<= 1) {
        int x = (t >= o) ? ts[t - o] : 0;
        __syncthreads();
        ts[t] += x;
        __syncthreads();
    }
    if (t == 255) bsum[blockIdx.x] = ts[255];
    int run = ts[t] - s;  // exclusive prefix of this thread within block
    if (base + 0 < n) out[base + 0] = run; run += v0;
    if (base + 1 < n) out[base + 1] = run; run += v1;
    if (base + 2 < n) out[base + 2] = run; run += v2;
    if (base + 3 < n) out[base + 3] = run;
}

// single-block exclusive scan, len <= 2048 (256 thr x 8)
__global__ void k_scan_block(const int* __restrict__ in, int* __restrict__ out, int len) {
    __shared__ int ts[256];
    int t = threadIdx.x;
    int v[8];
    int s = 0;
#pragma unroll
    for (int j = 0; j < 8; j++) {
        int i = t * 8 + j;
        v[j] = (i < len) ? in[i] : 0;
        s += v[j];
    }
    ts[t] = s;
    __syncthreads();
    for (int o = 1; o < 256; o <<= 1) {
        int x = (t >= o) ? ts[t - o] : 0;
        __syncthreads();
        ts[t] += x;
        __syncthreads();
    }
    int run = ts[t] - s;
#pragma unroll
    for (int j = 0; j < 8; j++) {
        int i = t * 8 + j;
        if (i < len) out[i] = run;
        run += v[j];
    }
}

__global__ void k_scan3(int* __restrict__ out, const int* __restrict__ bpre, int n) {
    int i = blockIdx.x * 256 + threadIdx.x;
    if (i < n) out[i] += bpre[i >> 10];
}

// -------------------- CSR fill --------------------
__global__ void k_fill(const int* __restrict__ src, const int* __restrict__ dst,
                       const int* __restrict__ off, int* __restrict__ cursor,
                       int* __restrict__ csr, int E) {
    int e = blockIdx.x * 256 + threadIdx.x;
    if (e < E) {
        int d = dst[e];
        int p = off[d] + atomicAdd(&cursor[d], 1);
        csr[p] = src[e];
    }
}

// -------------------- GEMM: u = dinv * (X @ W), K=13 --------------------
__global__ void k_gemm_in(const float* __restrict__ x, const float* __restrict__ W,
                          const float* __restrict__ dinv, float* __restrict__ u, int n) {
    __shared__ float Ws[N_FEAT * HID];
    for (int i = threadIdx.x; i < N_FEAT * HID; i += 256) Ws[i] = W[i];
    __syncthreads();
    int i = blockIdx.x * 2 + (threadIdx.x >> 7);
    int f = threadIdx.x & 127;
    if (i >= n) return;
    float acc = 0.f;
#pragma unroll
    for (int k = 0; k < N_FEAT; k++) acc += x[i * N_FEAT + k] * Ws[k * HID + f];
    u[(size_t)i * HID + f] = dinv[i] * acc;
}

// -------------------- GEMM: u = dinv * (X @ W), K=N=128 --------------------
// 32 nodes/block, 256 threads, each thread 4 nodes x 4 feats; W + X tile in LDS (80KB)
__global__ __launch_bounds__(256) void k_gemm128(const float* __restrict__ X,
                                                 const float* __restrict__ W,
                                                 const float* __restrict__ dinv,
                                                 float* __restrict__ U, int n) {
    __shared__ float Ws[HID * HID];   // 64 KB
    __shared__ float Xs[32 * HID];    // 16 KB
    int t = threadIdx.x;
    {
        const float4* W4 = (const float4*)W;
        float4* Ws4 = (float4*)Ws;
#pragma unroll
        for (int i = 0; i < 16; i++) Ws4[t + 256 * i] = W4[t + 256 * i];
    }
    int nb = blockIdx.x * 32;
    {
        const float4* X4 = (const float4*)X;
        float4* Xs4 = (float4*)Xs;
#pragma unroll
        for (int i = 0; i < 4; i++) {
            int idx = t + 256 * i;            // 1024 float4 total
            int node = idx >> 5, c4 = idx & 31;
            int g = nb + node;
            Xs4[idx] = (g < n) ? X4[(size_t)g * 32 + c4] : float4{0.f, 0.f, 0.f, 0.f};
        }
    }
    __syncthreads();

    int fg = (t & 31) * 4;
    int nl = (t >> 5) * 4;
    float acc[4][4];
#pragma unroll
    for (int j = 0; j < 4; j++)
#pragma unroll
        for (int q = 0; q < 4; q++) acc[j][q] = 0.f;

#pragma unroll 8
    for (int k = 0; k < HID; k++) {
        float4 w = *(const float4*)&Ws[k * HID + fg];
#pragma unroll
        for (int j = 0; j < 4; j++) {
            float xv = Xs[(nl + j) * HID + k];
            acc[j][0] += xv * w.x;
            acc[j][1] += xv * w.y;
            acc[j][2] += xv * w.z;
            acc[j][3] += xv * w.w;
        }
    }
#pragma unroll
    for (int j = 0; j < 4; j++) {
        int g = nb + nl + j;
        if (g < n) {
            float dv = dinv[g];
            float4 r = {dv * acc[j][0], dv * acc[j][1], dv * acc[j][2], dv * acc[j][3]};
            *(float4*)&U[(size_t)g * HID + fg] = r;
        }
    }
}

// -------------------- gather: y = relu?( dinv[d]*(sum_u + u[d]) + b ) --------------------
__global__ void k_gather(const float* __restrict__ u, const int* __restrict__ off,
                         const int* __restrict__ indeg, const int* __restrict__ csr,
                         const float* __restrict__ dinv, const float* __restrict__ bias,
                         float* __restrict__ y, int n, int relu) {
    int wv = threadIdx.x >> 6;
    int lane = threadIdx.x & 63;
    int d = blockIdx.x * 4 + wv;
    if (d >= n) return;
    int f = lane * 2;
    float2 acc = *(const float2*)&u[(size_t)d * HID + f];   // self term
    int s0 = off[d], c = indeg[d];
    for (int p = 0; p < c; p++) {
        int s = csr[s0 + p];
        float2 v = *(const float2*)&u[(size_t)s * HID + f];
        acc.x += v.x;
        acc.y += v.y;
    }
    float dv = dinv[d];
    float2 bb = *(const float2*)&bias[f];
    float ox = dv * acc.x + bb.x;
    float oy = dv * acc.y + bb.y;
    if (relu) { ox = fmaxf(ox, 0.f); oy = fmaxf(oy, 0.f); }
    *(float2*)&y[(size_t)d * HID + f] = float2{ox, oy};
}

// -------------------- pooling --------------------
__global__ void k_cnt(const int* __restrict__ batch, int* __restrict__ cnt, int n) {
    int i = blockIdx.x * 256 + threadIdx.x;
    if (i < n) atomicAdd(&cnt[batch[i]], 1);
}

// batch is sorted: nodes of graph g are [goff[g], goff[g]+cnt[g])
__global__ void k_pool(const float* __restrict__ h, const int* __restrict__ goff,
                       const int* __restrict__ cnt, float* __restrict__ pooledm) {
    int g = blockIdx.x;
    int t = threadIdx.x;   // 128
    int s = goff[g], c = cnt[g];
    float acc = 0.f;
    for (int i = s; i < s + c; i++) acc += h[(size_t)i * HID + t];
    pooledm[g * HID + t] = acc / (float)max(c, 1);
}

// -------------------- MLP head --------------------
__global__ void k_fc0(const float* __restrict__ in, const float* __restrict__ W,
                      const float* __restrict__ b, float* __restrict__ out) {
    __shared__ float row[128];
    int g = blockIdx.x, t = threadIdx.x;   // 256 threads
    if (t < 128) row[t] = in[g * 128 + t];
    __syncthreads();
    float acc = 0.f;
#pragma unroll 8
    for (int k = 0; k < 128; k++) acc += row[k] * W[k * 256 + t];
    acc += b[t];
    out[g * 256 + t] = fmaxf(acc, 0.f);
}

__global__ void k_fc1(const float* __restrict__ in, const float* __restrict__ W,
                      const float* __restrict__ b, float* __restrict__ out) {
    __shared__ float row[256];
    int g = blockIdx.x, t = threadIdx.x;   // 128 threads
    row[t] = in[g * 256 + t];
    row[t + 128] = in[g * 256 + t + 128];
    __syncthreads();
    float acc = 0.f;
#pragma unroll 8
    for (int k = 0; k < 256; k++) acc += row[k] * W[k * 128 + t];
    acc += b[t];
    out[g * 128 + t] = fmaxf(acc, 0.f);
}

__global__ void k_fco(const float* __restrict__ in, const float* __restrict__ Wo,
                      const float* __restrict__ bo, float* __restrict__ out) {
    int g = blockIdx.x, t = threadIdx.x;   // 64 threads = 1 wave
    float acc = in[g * 128 + t] * Wo[t] + in[g * 128 + 64 + t] * Wo[64 + t];
    for (int s = 32; s > 0; s >>= 1) acc += __shfl_down(acc, s);
    if (t == 0) out[g] = acc + bo[0];
}

// -------------------- launch --------------------
extern "C" void kernel_launch(void* const* d_in, const int* in_sizes, int n_in,
                              void* d_out, int out_size, void* d_ws, size_t ws_size,
                              hipStream_t stream) {
    const float* x   = (const float*)d_in[0];
    const int* ei    = (const int*)d_in[1];
    const int* src   = ei;
    const int* dst   = ei + N_EDGES;
    const int* batch = (const int*)d_in[2];
    const float* W0 = (const float*)d_in[3];  const float* b0 = (const float*)d_in[4];
    const float* W1 = (const float*)d_in[5];  const float* b1 = (const float*)d_in[6];
    const float* W2 = (const float*)d_in[7];  const float* b2 = (const float*)d_in[8];
    const float* Wf0 = (const float*)d_in[9];  const float* bf0 = (const float*)d_in[10];
    const float* Wf1 = (const float*)d_in[11]; const float* bf1 = (const float*)d_in[12];
    const float* Wo = (const float*)d_in[13];  const float* bo = (const float*)d_in[14];
    float* out = (float*)d_out;

    char* w = (char*)d_ws;
    size_t o = 0;
    auto take = [&](size_t bytes) -> char* {
        char* p = w + o;
        o += (bytes + 255) & ~(size_t)255;
        return p;
    };
    int* indeg    = (int*)take((size_t)N_NODES * 4);
    int* cursor   = (int*)take((size_t)N_NODES * 4);
    int* off      = (int*)take((size_t)N_NODES * 4);
    int* bsum     = (int*)take(256 * 4);
    int* bpre     = (int*)take(256 * 4);
    int* csr      = (int*)take((size_t)N_EDGES * 4);
    float* dinv   = (float*)take((size_t)N_NODES * 4);
    int* cnt      = (int*)take((size_t)N_GRAPHS * 4);
    int* goff     = (int*)take((size_t)N_GRAPHS * 4);
    float* bufA   = (float*)take((size_t)N_NODES * HID * 4);
    float* bufB   = (float*)take((size_t)N_NODES * HID * 4);
    float* pooledm= (float*)take((size_t)N_GRAPHS * HID * 4);
    float* fc0    = (float*)take((size_t)N_GRAPHS * 256 * 4);
    float* fc1    = (float*)take((size_t)N_GRAPHS * HID * 4);

    hipMemsetAsync(indeg, 0, (size_t)N_NODES * 4, stream);
    hipMemsetAsync(cursor, 0, (size_t)N_NODES * 4, stream);
    hipMemsetAsync(cnt, 0, (size_t)N_GRAPHS * 4, stream);

    // topology (shared by all 3 conv layers)
    k_deg<<<(N_EDGES + 255) / 256, 256, 0, stream>>>(dst, indeg, N_EDGES);
    int nb1 = (N_NODES + 1023) / 1024;
    k_scan1<<<nb1, 256, 0, stream>>>(indeg, off, bsum, N_NODES);
    k_scan_block<<<1, 256, 0, stream>>>(bsum, bpre, nb1);
    k_scan3<<<(N_NODES + 255) / 256, 256, 0, stream>>>(off, bpre, N_NODES);
    k_fill<<<(N_EDGES + 255) / 256, 256, 0, stream>>>(src, dst, off, cursor, csr, N_EDGES);
    k_dinv<<<(N_NODES + 255) / 256, 256, 0, stream>>>(indeg, dinv, N_NODES);
    k_cnt<<<(N_NODES + 255) / 256, 256, 0, stream>>>(batch, cnt, N_NODES);
    k_scan_block<<<1, 256, 0, stream>>>(cnt, goff, N_GRAPHS);

    // layer 0 (K=13)
    k_gemm_in<<<(N_NODES + 1) / 2, 256, 0, stream>>>(x, W0, dinv, bufB, N_NODES);
    k_gather<<<(N_NODES + 3) / 4, 256, 0, stream>>>(bufB, off, indeg, csr, dinv, b0, bufA, N_NODES, 1);
    // layer 1
    k_gemm128<<<(N_NODES + 31) / 32, 256, 0, stream>>>(bufA, W1, dinv, bufB, N_NODES);
    k_gather<<<(N_NODES + 3) / 4, 256, 0, stream>>>(bufB, off, indeg, csr, dinv, b1, bufA, N_NODES, 1);
    // layer 2 (no relu)
    k_gemm128<<<(N_NODES + 31) / 32, 256, 0, stream>>>(bufA, W2, dinv, bufB, N_NODES);
    k_gather<<<(N_NODES + 3) / 4, 256, 0, stream>>>(bufB, off, indeg, csr, dinv, b2, bufA, N_NODES, 0);

    // pool + MLP head
    k_pool<<<N_GRAPHS, 128, 0, stream>>>(bufA, goff, cnt, pooledm);
    k_fc0<<<N_GRAPHS, 256, 0, stream>>>(pooledm, Wf0, bf0, fc0);
    k_fc1<<<N_GRAPHS, 128, 0, stream>>>(fc0, Wf1, bf1, fc1);
    k_fco<<<N_GRAPHS, 64, 0, stream>>>(fc1, Wo, bo, out);
}

// Round 2
// 612.342 us; speedup vs baseline: 1.5280x; 1.5280x over previous
//
#include <hip/hip_runtime.h>
#include <hip/hip_bf16.h>

#define N_NODES  100000
#define N_EDGES  1600000
#define N_GRAPHS 2000
#define N_FEAT   13
#define HID      128

// -------------------- degree / dinv --------------------
__global__ void k_deg(const int* __restrict__ dst, int* __restrict__ indeg, int E) {
    int e = blockIdx.x * 256 + threadIdx.x;
    if (e < E) atomicAdd(&indeg[dst[e]], 1);
}

__global__ void k_dinv(const int* __restrict__ indeg, float* __restrict__ dinv, int n) {
    int i = blockIdx.x * 256 + threadIdx.x;
    if (i < n) dinv[i] = rsqrtf((float)(indeg[i] + 1));   // +1 self loop
}

// -------------------- scans (exclusive) --------------------
__global__ void k_scan1(const int* __restrict__ in, int* __restrict__ out,
                        int* __restrict__ bsum, int n) {
    __shared__ int ts[256];
    int t = threadIdx.x;
    int base = blockIdx.x * 1024 + t * 4;
    int v0 = (base + 0 < n) ? in[base + 0] : 0;
    int v1 = (base + 1 < n) ? in[base + 1] : 0;
    int v2 = (base + 2 < n) ? in[base + 2] : 0;
    int v3 = (base + 3 < n) ? in[base + 3] : 0;
    int s = v0 + v1 + v2 + v3;
    ts[t] = s;
    __syncthreads();
    for (int o = 1; o < 256; o <<= 1) {
        int x = (t >= o) ? ts[t - o] : 0;
        __syncthreads();
        ts[t] += x;
        __syncthreads();
    }
    if (t == 255) bsum[blockIdx.x] = ts[255];
    int run = ts[t] - s;
    if (base + 0 < n) out[base + 0] = run; run += v0;
    if (base + 1 < n) out[base + 1] = run; run += v1;
    if (base + 2 < n) out[base + 2] = run; run += v2;
    if (base + 3 < n) out[base + 3] = run;
}

__global__ void k_scan_block(const int* __restrict__ in, int* __restrict__ out, int len) {
    __shared__ int ts[256];
    int t = threadIdx.x;
    int v[8];
    int s = 0;
#pragma unroll
    for (int j = 0; j < 8; j++) {
        int i = t * 8 + j;
        v[j] = (i < len) ? in[i] : 0;
        s += v[j];
    }
    ts[t] = s;
    __syncthreads();
    for (int o = 1; o < 256; o <<= 1) {
        int x = (t >= o) ? ts[t - o] : 0;
        __syncthreads();
        ts[t] += x;
        __syncthreads();
    }
    int run = ts[t] - s;
#pragma unroll
    for (int j = 0; j < 8; j++) {
        int i = t * 8 + j;
        if (i < len) out[i] = run;
        run += v[j];
    }
}

__global__ void k_scan3(int* __restrict__ out, const int* __restrict__ bpre, int n) {
    int i = blockIdx.x * 256 + threadIdx.x;
    if (i < n) out[i] += bpre[i >> 10];
}

// -------------------- CSR fill --------------------
__global__ void k_fill(const int* __restrict__ src, const int* __restrict__ dst,
                       const int* __restrict__ off, int* __restrict__ cursor,
                       int* __restrict__ csr, int E) {
    int e = blockIdx.x * 256 + threadIdx.x;
    if (e < E) {
        int d = dst[e];
        int p = off[d] + atomicAdd(&cursor[d], 1);
        csr[p] = src[e];
    }
}

// -------------------- layer 0: xs = dinv * x, padded to 16 cols --------------------
__global__ void k_scale_pad(const float* __restrict__ x, const float* __restrict__ dinv,
                            float* __restrict__ xs, int n) {
    int i = blockIdx.x * 256 + threadIdx.x;
    if (i >= n) return;
    float dv = dinv[i];
    float r[16];
#pragma unroll
    for (int k = 0; k < N_FEAT; k++) r[k] = dv * x[i * N_FEAT + k];
    r[13] = r[14] = r[15] = 0.f;
    float4* o = (float4*)&xs[i * 16];
    o[0] = float4{r[0], r[1], r[2], r[3]};
    o[1] = float4{r[4], r[5], r[6], r[7]};
    o[2] = float4{r[8], r[9], r[10], r[11]};
    o[3] = float4{r[12], r[13], r[14], r[15]};
}

// -------------------- layer 0 gather on 16-wide rows (quarter-wave per dst) ----------
__global__ void k_gather13(const float* __restrict__ xs, const int* __restrict__ off,
                           const int* __restrict__ indeg, const int* __restrict__ csr,
                           const float* __restrict__ dinv, float* __restrict__ agg, int n) {
    int lane = threadIdx.x & 63;
    int q = lane >> 4, l4 = lane & 15;
    int d = blockIdx.x * 16 + (threadIdx.x >> 6) * 4 + q;
    if (d >= n) return;
    int s0 = off[d], c = indeg[d];
    float acc = xs[(size_t)d * 16 + l4];   // self term (already dinv[d]-scaled)
    int p = 0;
    for (; p + 3 < c; p += 4) {
        int sa = csr[s0 + p], sb = csr[s0 + p + 1];
        int sc_ = csr[s0 + p + 2], sd_ = csr[s0 + p + 3];
        float va = xs[(size_t)sa * 16 + l4];
        float vb = xs[(size_t)sb * 16 + l4];
        float vc = xs[(size_t)sc_ * 16 + l4];
        float vd = xs[(size_t)sd_ * 16 + l4];
        acc += (va + vb) + (vc + vd);
    }
    for (; p < c; p++) acc += xs[(size_t)csr[s0 + p] * 16 + l4];
    agg[(size_t)d * 16 + l4] = dinv[d] * acc;
}

// -------------------- layer 0 GEMM: h0 = relu(agg @ W0 + b0), K=13 --------------------
__global__ void k_gemm13(const float* __restrict__ agg, const float* __restrict__ W,
                         const float* __restrict__ b, float* __restrict__ h, int n) {
    __shared__ float Ws[N_FEAT * HID];
    for (int i = threadIdx.x; i < N_FEAT * HID; i += 256) Ws[i] = W[i];
    __syncthreads();
    int i = blockIdx.x * 2 + (threadIdx.x >> 7);
    int f = threadIdx.x & 127;
    if (i >= n) return;
    float acc = b[f];
#pragma unroll
    for (int k = 0; k < N_FEAT; k++) acc += agg[(size_t)i * 16 + k] * Ws[k * HID + f];
    h[(size_t)i * HID + f] = fmaxf(acc, 0.f);
}

// -------------------- fp32 -> bf16 RTNE --------------------
__device__ __forceinline__ unsigned short f2bf(float f) {
    unsigned int b = __float_as_uint(f);
    b += 0x7fffu + ((b >> 16) & 1u);
    return (unsigned short)(b >> 16);
}

// -------------------- GEMM 128x128: ubf = bf16( dinv * (X @ W) ) --------------------
__global__ __launch_bounds__(256) void k_gemm128(const float* __restrict__ X,
                                                 const float* __restrict__ W,
                                                 const float* __restrict__ dinv,
                                                 unsigned short* __restrict__ ubf, int n) {
    __shared__ float Ws[HID * HID];   // 64 KB
    __shared__ float Xs[32 * HID];    // 16 KB
    int t = threadIdx.x;
    {
        const float4* W4 = (const float4*)W;
        float4* Ws4 = (float4*)Ws;
#pragma unroll
        for (int i = 0; i < 16; i++) Ws4[t + 256 * i] = W4[t + 256 * i];
    }
    int nb = blockIdx.x * 32;
    {
        const float4* X4 = (const float4*)X;
        float4* Xs4 = (float4*)Xs;
#pragma unroll
        for (int i = 0; i < 4; i++) {
            int idx = t + 256 * i;
            int node = idx >> 5, c4 = idx & 31;
            int g = nb + node;
            Xs4[idx] = (g < n) ? X4[(size_t)g * 32 + c4] : float4{0.f, 0.f, 0.f, 0.f};
        }
    }
    __syncthreads();

    int fg = (t & 31) * 4;
    int nl = (t >> 5) * 4;
    float acc[4][4];
#pragma unroll
    for (int j = 0; j < 4; j++)
#pragma unroll
        for (int q = 0; q < 4; q++) acc[j][q] = 0.f;

#pragma unroll 8
    for (int k = 0; k < HID; k++) {
        float4 w = *(const float4*)&Ws[k * HID + fg];
#pragma unroll
        for (int j = 0; j < 4; j++) {
            float xv = Xs[(nl + j) * HID + k];
            acc[j][0] += xv * w.x;
            acc[j][1] += xv * w.y;
            acc[j][2] += xv * w.z;
            acc[j][3] += xv * w.w;
        }
    }
#pragma unroll
    for (int j = 0; j < 4; j++) {
        int g = nb + nl + j;
        if (g < n) {
            float dv = dinv[g];
            ushort4 r;
            r.x = f2bf(dv * acc[j][0]);
            r.y = f2bf(dv * acc[j][1]);
            r.z = f2bf(dv * acc[j][2]);
            r.w = f2bf(dv * acc[j][3]);
            *(ushort4*)&ubf[(size_t)g * HID + fg] = r;
        }
    }
}

// ---- gather over bf16 rows: y = relu?( dinv[d]*(sum_nbrs + self) + b ), fp32 out ----
// one wave per dst; half-wave handles even/odd neighbors; lane covers 4 feats (uint2)
__global__ void k_gather128(const unsigned int* __restrict__ ubf, const int* __restrict__ off,
                            const int* __restrict__ indeg, const int* __restrict__ csr,
                            const float* __restrict__ dinv, const float* __restrict__ bias,
                            float* __restrict__ y, int n, int relu) {
    int wv = threadIdx.x >> 6;
    int lane = threadIdx.x & 63;
    int d = blockIdx.x * 4 + wv;
    if (d >= n) return;
    int half = lane >> 5, l2 = lane & 31;
    int s0 = off[d], c = indeg[d];
    const uint2* U = (const uint2*)ubf;   // one row = 32 uint2 (128 bf16)
    float a0 = 0.f, a1 = 0.f, a2 = 0.f, a3 = 0.f;

    int p = half;
    for (; p + 2 < c; p += 4) {
        int sa = csr[s0 + p], sb = csr[s0 + p + 2];
        uint2 va = U[(size_t)sa * 32 + l2];
        uint2 vb = U[(size_t)sb * 32 + l2];
        a0 += __uint_as_float(va.x << 16) + __uint_as_float(vb.x << 16);
        a1 += __uint_as_float(va.x & 0xffff0000u) + __uint_as_float(vb.x & 0xffff0000u);
        a2 += __uint_as_float(va.y << 16) + __uint_as_float(vb.y << 16);
        a3 += __uint_as_float(va.y & 0xffff0000u) + __uint_as_float(vb.y & 0xffff0000u);
    }
    for (; p < c; p += 2) {
        int s = csr[s0 + p];
        uint2 v = U[(size_t)s * 32 + l2];
        a0 += __uint_as_float(v.x << 16);
        a1 += __uint_as_float(v.x & 0xffff0000u);
        a2 += __uint_as_float(v.y << 16);
        a3 += __uint_as_float(v.y & 0xffff0000u);
    }
    if (half) {   // self term once
        uint2 v = U[(size_t)d * 32 + l2];
        a0 += __uint_as_float(v.x << 16);
        a1 += __uint_as_float(v.x & 0xffff0000u);
        a2 += __uint_as_float(v.y << 16);
        a3 += __uint_as_float(v.y & 0xffff0000u);
    }
    a0 += __shfl_xor(a0, 32);
    a1 += __shfl_xor(a1, 32);
    a2 += __shfl_xor(a2, 32);
    a3 += __shfl_xor(a3, 32);
    if (!half) {
        float dv = dinv[d];
        float4 bb = *(const float4*)&bias[l2 * 4];
        float4 r = {dv * a0 + bb.x, dv * a1 + bb.y, dv * a2 + bb.z, dv * a3 + bb.w};
        if (relu) {
            r.x = fmaxf(r.x, 0.f); r.y = fmaxf(r.y, 0.f);
            r.z = fmaxf(r.z, 0.f); r.w = fmaxf(r.w, 0.f);
        }
        *(float4*)&y[(size_t)d * HID + l2 * 4] = r;
    }
}

// -------------------- pooling --------------------
__global__ void k_cnt(const int* __restrict__ batch, int* __restrict__ cnt, int n) {
    int i = blockIdx.x * 256 + threadIdx.x;
    if (i < n) atomicAdd(&cnt[batch[i]], 1);
}

__global__ void k_pool(const float* __restrict__ h, const int* __restrict__ goff,
                       const int* __restrict__ cnt, float* __restrict__ pooledm) {
    int g = blockIdx.x;
    int t = threadIdx.x;   // 128
    int s = goff[g], c = cnt[g];
    float acc = 0.f;
    for (int i = s; i < s + c; i++) acc += h[(size_t)i * HID + t];
    pooledm[g * HID + t] = acc / (float)max(c, 1);
}

// -------------------- MLP head --------------------
__global__ void k_fc0(const float* __restrict__ in, const float* __restrict__ W,
                      const float* __restrict__ b, float* __restrict__ out) {
    __shared__ float row[128];
    int g = blockIdx.x, t = threadIdx.x;   // 256 threads
    if (t < 128) row[t] = in[g * 128 + t];
    __syncthreads();
    float acc = 0.f;
#pragma unroll 8
    for (int k = 0; k < 128; k++) acc += row[k] * W[k * 256 + t];
    acc += b[t];
    out[g * 256 + t] = fmaxf(acc, 0.f);
}

__global__ void k_fc1(const float* __restrict__ in, const float* __restrict__ W,
                      const float* __restrict__ b, float* __restrict__ out) {
    __shared__ float row[256];
    int g = blockIdx.x, t = threadIdx.x;   // 128 threads
    row[t] = in[g * 256 + t];
    row[t + 128] = in[g * 256 + t + 128];
    __syncthreads();
    float acc = 0.f;
#pragma unroll 8
    for (int k = 0; k < 256; k++) acc += row[k] * W[k * 128 + t];
    acc += b[t];
    out[g * 128 + t] = fmaxf(acc, 0.f);
}

__global__ void k_fco(const float* __restrict__ in, const float* __restrict__ Wo,
                      const float* __restrict__ bo, float* __restrict__ out) {
    int g = blockIdx.x, t = threadIdx.x;   // 64 threads = 1 wave
    float acc = in[g * 128 + t] * Wo[t] + in[g * 128 + 64 + t] * Wo[64 + t];
    for (int s = 32; s > 0; s >>= 1) acc += __shfl_down(acc, s);
    if (t == 0) out[g] = acc + bo[0];
}

// -------------------- launch --------------------
extern "C" void kernel_launch(void* const* d_in, const int* in_sizes, int n_in,
                              void* d_out, int out_size, void* d_ws, size_t ws_size,
                              hipStream_t stream) {
    const float* x   = (const float*)d_in[0];
    const int* ei    = (const int*)d_in[1];
    const int* src   = ei;
    const int* dst   = ei + N_EDGES;
    const int* batch = (const int*)d_in[2];
    const float* W0 = (const float*)d_in[3];  const float* b0 = (const float*)d_in[4];
    const float* W1 = (const float*)d_in[5];  const float* b1 = (const float*)d_in[6];
    const float* W2 = (const float*)d_in[7];  const float* b2 = (const float*)d_in[8];
    const float* Wf0 = (const float*)d_in[9];  const float* bf0 = (const float*)d_in[10];
    const float* Wf1 = (const float*)d_in[11]; const float* bf1 = (const float*)d_in[12];
    const float* Wo = (const float*)d_in[13];  const float* bo = (const float*)d_in[14];
    float* out = (float*)d_out;

    char* w = (char*)d_ws;
    size_t o = 0;
    auto take = [&](size_t bytes) -> char* {
        char* p = w + o;
        o += (bytes + 255) & ~(size_t)255;
        return p;
    };
    int* indeg    = (int*)take((size_t)N_NODES * 4);
    int* cursor   = (int*)take((size_t)N_NODES * 4);
    int* off      = (int*)take((size_t)N_NODES * 4);
    int* bsum     = (int*)take(256 * 4);
    int* bpre     = (int*)take(256 * 4);
    int* csr      = (int*)take((size_t)N_EDGES * 4);
    float* dinv   = (float*)take((size_t)N_NODES * 4);
    int* cnt      = (int*)take((size_t)N_GRAPHS * 4);
    int* goff     = (int*)take((size_t)N_GRAPHS * 4);
    float* bufA   = (float*)take((size_t)N_NODES * HID * 4);
    float* bufB   = (float*)take((size_t)N_NODES * HID * 4);
    unsigned short* ubf = (unsigned short*)take((size_t)N_NODES * HID * 2);
    float* pooledm= (float*)take((size_t)N_GRAPHS * HID * 4);
    float* fc0    = (float*)take((size_t)N_GRAPHS * 256 * 4);
    float* fc1    = (float*)take((size_t)N_GRAPHS * HID * 4);
    // xs/agg alias the head of bufB (dead before first gather128 write to bufB)
    float* xs  = bufB;
    float* agg = bufB + (size_t)N_NODES * 16;

    hipMemsetAsync(indeg, 0, (size_t)N_NODES * 4, stream);
    hipMemsetAsync(cursor, 0, (size_t)N_NODES * 4, stream);
    hipMemsetAsync(cnt, 0, (size_t)N_GRAPHS * 4, stream);

    // topology (shared by all 3 conv layers)
    k_deg<<<(N_EDGES + 255) / 256, 256, 0, stream>>>(dst, indeg, N_EDGES);
    int nb1 = (N_NODES + 1023) / 1024;
    k_scan1<<<nb1, 256, 0, stream>>>(indeg, off, bsum, N_NODES);
    k_scan_block<<<1, 256, 0, stream>>>(bsum, bpre, nb1);
    k_scan3<<<(N_NODES + 255) / 256, 256, 0, stream>>>(off, bpre, N_NODES);
    k_fill<<<(N_EDGES + 255) / 256, 256, 0, stream>>>(src, dst, off, cursor, csr, N_EDGES);
    k_dinv<<<(N_NODES + 255) / 256, 256, 0, stream>>>(indeg, dinv, N_NODES);
    k_cnt<<<(N_NODES + 255) / 256, 256, 0, stream>>>(batch, cnt, N_NODES);
    k_scan_block<<<1, 256, 0, stream>>>(cnt, goff, N_GRAPHS);

    // layer 0: aggregate 13-wide first, then GEMM
    k_scale_pad<<<(N_NODES + 255) / 256, 256, 0, stream>>>(x, dinv, xs, N_NODES);
    k_gather13<<<(N_NODES + 15) / 16, 256, 0, stream>>>(xs, off, indeg, csr, dinv, agg, N_NODES);
    k_gemm13<<<(N_NODES + 1) / 2, 256, 0, stream>>>(agg, W0, b0, bufA, N_NODES);
    // layer 1
    k_gemm128<<<(N_NODES + 31) / 32, 256, 0, stream>>>(bufA, W1, dinv, ubf, N_NODES);
    k_gather128<<<(N_NODES + 3) / 4, 256, 0, stream>>>((const unsigned int*)ubf, off, indeg, csr, dinv, b1, bufB, N_NODES, 1);
    // layer 2 (no relu)
    k_gemm128<<<(N_NODES + 31) / 32, 256, 0, stream>>>(bufB, W2, dinv, ubf, N_NODES);
    k_gather128<<<(N_NODES + 3) / 4, 256, 0, stream>>>((const unsigned int*)ubf, off, indeg, csr, dinv, b2, bufA, N_NODES, 0);

    // pool + MLP head
    k_pool<<<N_GRAPHS, 128, 0, stream>>>(bufA, goff, cnt, pooledm);
    k_fc0<<<N_GRAPHS, 256, 0, stream>>>(pooledm, Wf0, bf0, fc0);
    k_fc1<<<N_GRAPHS, 128, 0, stream>>>(fc0, Wf1, bf1, fc1);
    k_fco<<<N_GRAPHS, 64, 0, stream>>>(fc1, Wo, bo, out);
}